// Round 15
// baseline (17302.711 us; speedup 1.0000x reference)
//
#include <hip/hip_runtime.h>

// MultiLayerRNN: B=128, T=1024, D_IN=256, H=512, C=1000
// Round 15: chain multiplexing (M=4) with DRAIN-ALL semantics only.
// r13/r14's NaN attributed to the counted-vmcnt ledger (fragile to any
// compiler-inserted VMEM between asm blocks). This round: every wait is
// s_waitcnt vmcnt(0) -- the exact semantics of the passing r9-r12 kernels.
// Single-buffered BODY: issue 18 loads -> drain -> validate (data-as-flag,
// bounded retry) -> 32 MFMA (aux as C-in) -> encoded stores (fire-and-forget;
// next BODY's drain covers them). 24 WGs x 256 thr = 2 groups x 3 stages x
// 4 column-quarters; ~240 VGPR (wB 128 + X 64 + misc).

typedef __attribute__((ext_vector_type(8))) short bf16x8_t;
typedef __attribute__((ext_vector_type(4))) float f32x4;
typedef __attribute__((ext_vector_type(4))) unsigned u32x4;
typedef unsigned long long u64;

#define NCH 8u
#define SPIN_CAP (1u << 14)

__device__ __align__(16) unsigned short g_W[3][512 * 512];   // bf16 [n][k]: Wh0, Wx1, Wh1
__device__ float g_b1[512];
__device__ __align__(16) unsigned short g_pre0T[1024u * 512u * 128u]; // bf16 [t][c][128r]
__device__ __align__(16) unsigned short g_h0H[NCH][1025][8192];       // slot s = ~h0[s-1], [16r][512c]
__device__ __align__(16) unsigned short g_h1H[NCH][1025][8192];       // slot s = ~h1[s-1]
__device__ __align__(16) unsigned g_UH[NCH][1024][8192];              // [t][512c][16r] ~f32bits

__device__ __forceinline__ unsigned short f2bf(float f) {
  unsigned u = __float_as_uint(f);
  u += 0x7fffu + ((u >> 16) & 1u);   // RNE
  return (unsigned short)(u >> 16);
}
__device__ __forceinline__ float bf2f(unsigned short h) {
  return __uint_as_float(((unsigned)h) << 16);
}
__device__ __forceinline__ bf16x8_t cvt8f(const float* p) {
  bf16x8_t r;
#pragma unroll
  for (int i = 0; i < 8; ++i) r[i] = (short)f2bf(p[i]);
  return r;
}
__device__ __forceinline__ float tanh_fast(float x) {
  float e = __expf(2.f * x);
  return 1.f - 2.f / (e + 1.f);
}

#define MF(a, b, c) __builtin_amdgcn_mfma_f32_16x16x32_bf16(a, b, c, 0, 0, 0)
#define WAITV0 do { asm volatile("s_waitcnt vmcnt(0)" ::: "memory"); __builtin_amdgcn_sched_barrier(0); } while (0)

// off-form 64-bit per-lane vaddr; sc1 = IC-coherent (validated r4/r5/r9-r12)
#define LDG16(dst, base, OFF) \
  asm volatile("global_load_dwordx4 %0, %1, off offset:" #OFF " sc1" : "=v"(dst) : "v"(base))
#define LD8(dst, base) \
  asm volatile("global_load_dwordx2 %0, %1, off" : "=v"(dst) : "v"(base))
#define ST2(base, OFF, val) \
  asm volatile("global_store_short %0, %1, off offset:" #OFF " sc1" :: "v"(base), "v"(val))
#define ST16(base, OFF, val) \
  asm volatile("global_store_dwordx4 %0, %1, off offset:" #OFF " sc1" :: "v"(base), "v"(val))

__device__ __forceinline__ bool vfrag(bf16x8_t v) {
  union { bf16x8_t b; unsigned u[4]; } t; t.b = v;
  bool ok = true;
#pragma unroll
  for (int i = 0; i < 4; ++i) ok = ok && ((t.u[i] & 0xFFFFu) != 0u) && ((t.u[i] >> 16) != 0u);
  return ok;
}
__device__ __forceinline__ bool vu4(u32x4 v) {
  return (v[0] != 0u) && (v[1] != 0u) && (v[2] != 0u) && (v[3] != 0u);
}
__device__ __forceinline__ bf16x8_t dec(bf16x8_t v) {
  union { bf16x8_t b; unsigned u[4]; } t; t.b = v;
#pragma unroll
  for (int i = 0; i < 4; ++i) t.u[i] = ~t.u[i];
  return t.b;
}
__device__ __forceinline__ f32x4 decf(u32x4 v) {
  f32x4 r;
#pragma unroll
  for (int i = 0; i < 4; ++i) r[i] = __uint_as_float(~v[i]);
  return r;
}
__device__ __forceinline__ f32x4 p2f4(u64 p) {  // pre0 bits (plain bf16)
  f32x4 r;
#pragma unroll
  for (int i = 0; i < 4; ++i) r[i] = bf2f((unsigned short)(p >> (16 * i)));
  return r;
}

// ---------------------------------------------------------------- prep
__global__ void prep_kernel(const float* __restrict__ Wh0_w, const float* __restrict__ Wx1_w,
                            const float* __restrict__ Wh1_w, const float* __restrict__ Wx1_b,
                            const float* __restrict__ Wh1_b) {
  size_t tid = (size_t)blockIdx.x * blockDim.x + threadIdx.x;
  size_t stride = (size_t)gridDim.x * blockDim.x;
  for (size_t i = tid; i < 512u * 512u; i += stride) {
    g_W[0][i] = f2bf(Wh0_w[i]);
    g_W[1][i] = f2bf(Wx1_w[i]);
    g_W[2][i] = f2bf(Wh1_w[i]);
  }
  for (size_t i = tid; i < 512u; i += stride) g_b1[i] = Wx1_b[i] + Wh1_b[i];
  uint4 z = {0u, 0u, 0u, 0u};
  uint4 f = {~0u, ~0u, ~0u, ~0u};
  for (size_t i = tid; i < NCH * 1024u; i += stride) {     // slot 0 = encoded h=0
    size_t ch = i >> 10, o = i & 1023u;
    ((uint4*)&g_h0H[ch][0][0])[o] = f;
    ((uint4*)&g_h1H[ch][0][0])[o] = f;
  }
  size_t n1 = (size_t)NCH * 1024u * 1024u;                 // slots 1..1024 invalid (0)
  for (size_t i = tid; i < n1; i += stride) {
    size_t ch = i >> 20, o = i & ((1u << 20) - 1u);
    ((uint4*)&g_h0H[ch][1][0])[o] = z;
    ((uint4*)&g_h1H[ch][1][0])[o] = z;
  }
  uint4* pu = (uint4*)&g_UH[0][0][0];
  size_t nu = sizeof(g_UH) / 16u;
  for (size_t i = tid; i < nu; i += stride) pu[i] = z;
}

// ---------------------------------------------------------------- pre0: x @ Wx0^T + biases -> [t][c][128r]
__global__ __launch_bounds__(512) void pre0_kernel(const float* __restrict__ x,
                                                   const float* __restrict__ Wx0_w,
                                                   const float* __restrict__ Wx0_b,
                                                   const float* __restrict__ Wh0_b) {
  const unsigned t = blockIdx.x;
  const unsigned lane = threadIdx.x & 63u, w = threadIdx.x >> 6;
  const unsigned lrow = lane & 15u, lko = (lane >> 4) * 8u, crow = (lane >> 4) * 4u;
  const unsigned ncol0 = w * 64u;
  f32x4 z4 = {0.f, 0.f, 0.f, 0.f};
  f32x4 acc[8][4];
#pragma unroll
  for (int a = 0; a < 8; ++a)
#pragma unroll
    for (int b = 0; b < 4; ++b) acc[a][b] = z4;

  for (unsigned kk = 0; kk < 8u; ++kk) {
    unsigned k0 = kk * 32u + lko;
    bf16x8_t bfr[4];
#pragma unroll
    for (unsigned nj = 0; nj < 4u; ++nj) {
      unsigned n = ncol0 + nj * 16u + lrow;
      bfr[nj] = cvt8f(Wx0_w + n * 256u + k0);
    }
#pragma unroll
    for (unsigned mi = 0; mi < 8u; ++mi) {
      unsigned m = mi * 16u + lrow;
      bf16x8_t afr = cvt8f(x + ((size_t)m * 1024u + t) * 256u + k0);
#pragma unroll
      for (unsigned nj = 0; nj < 4u; ++nj)
        acc[mi][nj] = MF(afr, bfr[nj], acc[mi][nj]);
    }
  }
#pragma unroll
  for (unsigned mi = 0; mi < 8u; ++mi)
#pragma unroll
    for (unsigned nj = 0; nj < 4u; ++nj) {
      unsigned col = ncol0 + nj * 16u + lrow;
      u64 pv = 0ull;
#pragma unroll
      for (unsigned r = 0; r < 4u; ++r) {
        float v = acc[mi][nj][r] + Wx0_b[col] + Wh0_b[col];
        pv |= ((u64)f2bf(v)) << (16u * r);
      }
      *(u64*)(&g_pre0T[((size_t)t * 512u + col) * 128u + mi * 16u + crow]) = pv;
    }
}

// ---------------------------------------------------------------- multiplexed persistent loop
// STAGE: 0 = L0 (h0 loop + pre0), 1 = U (h0@Wx1^T + b1), 2 = C (h1 loop + U)

#define LDALL(A) \
  LDG16(X0,(A),0);   LDG16(X1,(A),64);  LDG16(X2,(A),128);  LDG16(X3,(A),192); \
  LDG16(X4,(A),256); LDG16(X5,(A),320); LDG16(X6,(A),384);  LDG16(X7,(A),448); \
  LDG16(X8,(A),512); LDG16(X9,(A),576); LDG16(X10,(A),640); LDG16(X11,(A),704); \
  LDG16(X12,(A),768); LDG16(X13,(A),832); LDG16(X14,(A),896); LDG16(X15,(A),960)

#define VALL() (vfrag(X0)&&vfrag(X1)&&vfrag(X2)&&vfrag(X3)&& \
                vfrag(X4)&&vfrag(X5)&&vfrag(X6)&&vfrag(X7)&& \
                vfrag(X8)&&vfrag(X9)&&vfrag(X10)&&vfrag(X11)&& \
                vfrag(X12)&&vfrag(X13)&&vfrag(X14)&&vfrag(X15))

#define DECALL() \
  X0=dec(X0); X1=dec(X1); X2=dec(X2); X3=dec(X3); \
  X4=dec(X4); X5=dec(X5); X6=dec(X6); X7=dec(X7); \
  X8=dec(X8); X9=dec(X9); X10=dec(X10); X11=dec(X11); \
  X12=dec(X12); X13=dec(X13); X14=dec(X14); X15=dec(X15)

#define MF2(F) do { acc0 = MF(X##F, wB[0][F], acc0); acc1 = MF(X##F, wB[1][F], acc1); } while (0)
#define MFALL() \
  MF2(0); MF2(1); MF2(2); MF2(3); MF2(4); MF2(5); MF2(6); MF2(7); \
  MF2(8); MF2(9); MF2(10); MF2(11); MF2(12); MF2(13); MF2(14); MF2(15)

// A-source byte address for (CH, TT) by stage
#define ADDR_A(CH, TT) \
  ((STAGE == 0) ? ((const char*)g_h0H + ((size_t)(CH) * 1025u + (TT)) * 16384u + voffA) \
   : (STAGE == 1) ? ((const char*)g_h0H + ((size_t)(CH) * 1025u + (TT) + 1u) * 16384u + voffA) \
                  : ((const char*)g_h1H + ((size_t)(CH) * 1025u + (TT)) * 16384u + voffA))

template<int STAGE>
__device__ __forceinline__ void run_role(unsigned g4, unsigned q) {
  const unsigned tid = threadIdx.x;
  const unsigned lane = tid & 63u, w = tid >> 6;              // 4 waves
  const unsigned lrow = lane & 15u, kq = (lane >> 4) * 8u, crow4 = (lane >> 4) * 4u;
  const unsigned colbase = q * 128u + w * 32u;                // wave's 32 output cols

  // ---- weights -> VGPRs once: wB[cj][f] for cols colbase+cj*16+lrow (128 VGPR) ----
  bf16x8_t wB[2][16];
  {
    const unsigned short* wp = g_W[STAGE];
#pragma unroll
    for (int cj = 0; cj < 2; ++cj)
#pragma unroll
      for (int f = 0; f < 16; ++f) {
        unsigned n = colbase + (unsigned)cj * 16u + lrow;
        wB[cj][f] = *(const bf16x8_t*)(wp + ((size_t)n * 512u + (unsigned)f * 32u + kq));
      }
  }
  float bU0 = 0.f, bU1 = 0.f;
  if (STAGE == 1) {
    bU0 = g_b1[colbase + lrow];
    bU1 = g_b1[colbase + 16u + lrow];
  }

  // ---- per-lane byte offsets ----
  const unsigned voffA = lrow * 1024u + kq * 2u;                       // within h slot
  const unsigned voffO = crow4 * 1024u + (colbase + lrow) * 2u;        // h store
  const unsigned voffU = (colbase + lrow) * 64u + crow4 * 4u;          // U load/store
  const unsigned voffP = (colbase + lrow) * 256u + crow4 * 2u;         // pre0

  bf16x8_t X0, X1, X2, X3, X4, X5, X6, X7, X8, X9, X10, X11, X12, X13, X14, X15;
  u64 P0 = 0, P1 = 0;
  u32x4 U0 = {0,0,0,0}, U1 = {0,0,0,0};
  f32x4 acc0, acc1;

  for (unsigned i = 0; i < 4096u; ++i) {
    const unsigned t_ = i >> 2, ch_ = g4 + (i & 3u);

    // ---- issue this body's loads, then drain everything (incl. prev stores) ----
    const char* aA = ADDR_A(ch_, t_);
    LDALL(aA);
    if constexpr (STAGE == 0) {
      const char* pc = (const char*)g_pre0T + (size_t)t_ * 131072u + voffP + ch_ * 32u;
      LD8(P0, pc); LD8(P1, pc + 4096);
    } else if constexpr (STAGE == 2) {
      const char* uA = (const char*)g_UH + ((size_t)ch_ * 1024u + t_) * 32768u + voffU;
      LDG16(U0, uA, 0); LDG16(U1, uA, 1024);
    }
    WAITV0;

    // ---- validate A (data-as-flag), bounded retry ----
    {
      bool ok = VALL();
      unsigned sp = 0;
      while (__any(!ok) && ++sp < SPIN_CAP) {
        LDALL(aA);
        WAITV0;
        ok = VALL();
      }
    }
    DECALL();

    // ---- acc init (pre0 / bias / U as MFMA C-in) ----
    if constexpr (STAGE == 0) {
      acc0 = p2f4(P0); acc1 = p2f4(P1);
    } else if constexpr (STAGE == 1) {
      acc0 = (f32x4){bU0, bU0, bU0, bU0}; acc1 = (f32x4){bU1, bU1, bU1, bU1};
    } else {
      bool okU = vu4(U0) && vu4(U1);
      unsigned spu = 0;
      while (__any(!okU) && ++spu < SPIN_CAP) {
        const char* uA = (const char*)g_UH + ((size_t)ch_ * 1024u + t_) * 32768u + voffU;
        LDG16(U0, uA, 0); LDG16(U1, uA, 1024);
        WAITV0;
        okU = vu4(U0) && vu4(U1);
      }
      acc0 = decf(U0); acc1 = decf(U1);
    }

    MFALL();

    // ---- epilogue: encoded stores, fire-and-forget (next WAITV0 drains) ----
    if constexpr (STAGE == 1) {
      char* uo = (char*)g_UH + ((size_t)ch_ * 1024u + t_) * 32768u + voffU;
      u32x4 o;
      o[0] = ~__float_as_uint(acc0[0]); o[1] = ~__float_as_uint(acc0[1]);
      o[2] = ~__float_as_uint(acc0[2]); o[3] = ~__float_as_uint(acc0[3]); ST16(uo, 0, o);
      o[0] = ~__float_as_uint(acc1[0]); o[1] = ~__float_as_uint(acc1[1]);
      o[2] = ~__float_as_uint(acc1[2]); o[3] = ~__float_as_uint(acc1[3]); ST16(uo, 1024, o);
    } else {
      char* ho = (char*)((STAGE == 0) ? g_h0H : g_h1H)
                 + ((size_t)ch_ * 1025u + t_ + 1u) * 16384u + voffO;
      unsigned e;
      e = f2bf(tanh_fast(acc0[0])) ^ 0xFFFFu; ST2(ho, 0, e);
      e = f2bf(tanh_fast(acc0[1])) ^ 0xFFFFu; ST2(ho, 1024, e);
      e = f2bf(tanh_fast(acc0[2])) ^ 0xFFFFu; ST2(ho, 2048, e);
      e = f2bf(tanh_fast(acc0[3])) ^ 0xFFFFu; ST2(ho, 3072, e);
      e = f2bf(tanh_fast(acc1[0])) ^ 0xFFFFu; ST2(ho, 32, e);
      e = f2bf(tanh_fast(acc1[1])) ^ 0xFFFFu; ST2(ho, 1056, e);
      e = f2bf(tanh_fast(acc1[2])) ^ 0xFFFFu; ST2(ho, 2080, e);
      e = f2bf(tanh_fast(acc1[3])) ^ 0xFFFFu; ST2(ho, 3104, e);
    }
  }
  WAITV0;   // drain final stores
}

__global__ __launch_bounds__(256, 1) void rnn_kernel() {
  const unsigned wg = blockIdx.x;            // 24 WGs
  const unsigned g4 = (wg / 12u) * 4u;       // chain group base (0 or 4)
  const unsigned r = wg % 12u;
  const unsigned stage = r >> 2, q = r & 3u; // 3 stages x 4 column-quarters
  if (stage == 0u) run_role<0>(g4, q);
  else if (stage == 1u) run_role<1>(g4, q);
  else run_role<2>(g4, q);
}

// ---------------------------------------------------------------- fc: h1_final @ fc_w^T + fc_b
__global__ __launch_bounds__(256) void fc_kernel(const float* __restrict__ fc_w,
                                                 const float* __restrict__ fc_b,
                                                 float* __restrict__ out) {
  const unsigned wg = blockIdx.x;
  const unsigned lane = threadIdx.x & 63u, w = threadIdx.x >> 6;
  const unsigned lrow = lane & 15u, lko = (lane >> 4) * 8u, crow = (lane >> 4) * 4u;
  const unsigned n0 = wg * 64u + w * 16u;
  f32x4 z4 = {0.f, 0.f, 0.f, 0.f};
  f32x4 acc[8];
#pragma unroll
  for (int a = 0; a < 8; ++a) acc[a] = z4;
  const unsigned n = n0 + lrow;
  for (unsigned kk = 0; kk < 16u; ++kk) {
    unsigned k0 = kk * 32u + lko;
    bf16x8_t bfr = {0, 0, 0, 0, 0, 0, 0, 0};
    if (n < 1000u) bfr = cvt8f(fc_w + n * 512u + k0);
#pragma unroll
    for (unsigned mi = 0; mi < 8u; ++mi) {
      bf16x8_t afr = dec(*(const bf16x8_t*)(&g_h1H[mi][1024][lrow * 512u + k0]));  // ~h1[1023]
      acc[mi] = MF(afr, bfr, acc[mi]);
    }
  }
#pragma unroll
  for (unsigned mi = 0; mi < 8u; ++mi)
#pragma unroll
    for (unsigned rr = 0; rr < 4u; ++rr) {
      unsigned row = mi * 16u + crow + rr;
      unsigned col = n0 + lrow;
      if (col < 1000u) out[row * 1000u + col] = acc[mi][rr] + fc_b[col];
    }
}

// ---------------------------------------------------------------- launch
extern "C" void kernel_launch(void* const* d_in, const int* in_sizes, int n_in,
                              void* d_out, int out_size, void* d_ws, size_t ws_size,
                              hipStream_t stream) {
  (void)in_sizes; (void)n_in; (void)out_size; (void)d_ws; (void)ws_size;
  const float* x     = (const float*)d_in[0];
  const float* Wx0_w = (const float*)d_in[1];
  const float* Wx0_b = (const float*)d_in[2];
  const float* Wh0_w = (const float*)d_in[3];
  const float* Wh0_b = (const float*)d_in[4];
  const float* Wx1_w = (const float*)d_in[5];
  const float* Wx1_b = (const float*)d_in[6];
  const float* Wh1_w = (const float*)d_in[7];
  const float* Wh1_b = (const float*)d_in[8];
  const float* fc_w  = (const float*)d_in[9];
  const float* fc_b  = (const float*)d_in[10];

  prep_kernel<<<1024, 256, 0, stream>>>(Wh0_w, Wx1_w, Wh1_w, Wx1_b, Wh1_b);
  pre0_kernel<<<1024, 512, 0, stream>>>(x, Wx0_w, Wx0_b, Wh0_b);
  rnn_kernel<<<24, 256, 0, stream>>>();
  fc_kernel<<<16, 256, 0, stream>>>(fc_w, fc_b, (float*)d_out);
}

// Round 16
// 3275.385 us; speedup vs baseline: 5.2826x; 5.2826x over previous
//
#include <hip/hip_runtime.h>

// MultiLayerRNN: B=128, T=1024, D_IN=256, H=512, C=1000
// Round 16: COOPERATIVE cross-WG loads. r12 structure, but the sibling h-half
// (8KB) is loaded by the WG cooperatively -- ONE sc1 16B load per thread --
// validated per-chunk (data-as-flag), decoded, staged to swizzled LDS; waves
// ds_read fragments. U stage: full h0 slot (16KB) = 2 chunks/thread. This
// removes the 16x-per-wave redundant sc1 load streams that r15 isolated as
// ~4.2us/body of pure mechanics.
//   48 WGs x 512 thr: {L0A,L0B,UA,UB,CA,CB} x 8 chains. Own half via LDS
//   (r11/12), full-history buffers (no WAR), drain-all waits only.

typedef __attribute__((ext_vector_type(8))) short bf16x8_t;
typedef __attribute__((ext_vector_type(4))) float f32x4;
typedef __attribute__((ext_vector_type(4))) unsigned u32x4;
typedef unsigned long long u64;

#define NCH 8u
#define SPIN_CAP (1u << 14)

__device__ __align__(16) unsigned short g_W[3][512 * 512];   // bf16 [n][k]: Wh0, Wx1, Wh1
__device__ float g_b1[512];
__device__ __align__(16) unsigned short g_pre0T[1024u * 512u * 128u]; // bf16 [t][c][128r]
__device__ __align__(16) unsigned short g_h0H[NCH][1025][8192];       // slot s = ~h0[s-1], [16r][512c]
__device__ __align__(16) unsigned short g_h1H[NCH][1025][8192];       // slot s = ~h1[s-1]
__device__ __align__(16) unsigned g_UH[NCH][1024][8192];              // [t][512c][16r] ~f32bits

__device__ __forceinline__ unsigned short f2bf(float f) {
  unsigned u = __float_as_uint(f);
  u += 0x7fffu + ((u >> 16) & 1u);   // RNE
  return (unsigned short)(u >> 16);
}
__device__ __forceinline__ float bf2f(unsigned short h) {
  return __uint_as_float(((unsigned)h) << 16);
}
__device__ __forceinline__ bf16x8_t cvt8f(const float* p) {
  bf16x8_t r;
#pragma unroll
  for (int i = 0; i < 8; ++i) r[i] = (short)f2bf(p[i]);
  return r;
}
__device__ __forceinline__ float tanh_fast(float x) {
  float e = __expf(2.f * x);
  return 1.f - 2.f / (e + 1.f);
}

#define MF(a, b, c) __builtin_amdgcn_mfma_f32_16x16x32_bf16(a, b, c, 0, 0, 0)
#define WAITV0 do { asm volatile("s_waitcnt vmcnt(0)" ::: "memory"); __builtin_amdgcn_sched_barrier(0); } while (0)

// off-form 64-bit per-lane vaddr; sc1 = IC-coherent (validated r4/r5/r9-r15)
#define LDG16(dst, base, OFF) \
  asm volatile("global_load_dwordx4 %0, %1, off offset:" #OFF " sc1" : "=v"(dst) : "v"(base))
#define ST16(base, OFF, val) \
  asm volatile("global_store_dwordx4 %0, %1, off offset:" #OFF " sc1" :: "v"(base), "v"(val))

__device__ __forceinline__ bool vfrag(bf16x8_t v) {
  union { bf16x8_t b; unsigned u[4]; } t; t.b = v;
  bool ok = true;
#pragma unroll
  for (int i = 0; i < 4; ++i) ok = ok && ((t.u[i] & 0xFFFFu) != 0u) && ((t.u[i] >> 16) != 0u);
  return ok;
}
__device__ __forceinline__ bool vu4(u32x4 v) {
  return (v[0] != 0u) && (v[1] != 0u) && (v[2] != 0u) && (v[3] != 0u);
}
__device__ __forceinline__ bf16x8_t dec(bf16x8_t v) {
  union { bf16x8_t b; unsigned u[4]; } t; t.b = v;
#pragma unroll
  for (int i = 0; i < 4; ++i) t.u[i] = ~t.u[i];
  return t.b;
}
__device__ __forceinline__ f32x4 decf(u32x4 v) {
  f32x4 r;
#pragma unroll
  for (int i = 0; i < 4; ++i) r[i] = __uint_as_float(~v[i]);
  return r;
}

// ---------------------------------------------------------------- prep
__global__ void prep_kernel(const float* __restrict__ Wh0_w, const float* __restrict__ Wx1_w,
                            const float* __restrict__ Wh1_w, const float* __restrict__ Wx1_b,
                            const float* __restrict__ Wh1_b) {
  size_t tid = (size_t)blockIdx.x * blockDim.x + threadIdx.x;
  size_t stride = (size_t)gridDim.x * blockDim.x;
  for (size_t i = tid; i < 512u * 512u; i += stride) {
    g_W[0][i] = f2bf(Wh0_w[i]);
    g_W[1][i] = f2bf(Wx1_w[i]);
    g_W[2][i] = f2bf(Wh1_w[i]);
  }
  for (size_t i = tid; i < 512u; i += stride) g_b1[i] = Wx1_b[i] + Wh1_b[i];
  uint4 z = {0u, 0u, 0u, 0u};
  uint4 f = {~0u, ~0u, ~0u, ~0u};
  for (size_t i = tid; i < NCH * 1024u; i += stride) {     // slot 0 = encoded h=0
    size_t ch = i >> 10, o = i & 1023u;
    ((uint4*)&g_h0H[ch][0][0])[o] = f;
    ((uint4*)&g_h1H[ch][0][0])[o] = f;
  }
  size_t n1 = (size_t)NCH * 1024u * 1024u;                 // slots 1..1024 invalid (0)
  for (size_t i = tid; i < n1; i += stride) {
    size_t ch = i >> 20, o = i & ((1u << 20) - 1u);
    ((uint4*)&g_h0H[ch][1][0])[o] = z;
    ((uint4*)&g_h1H[ch][1][0])[o] = z;
  }
  uint4* pu = (uint4*)&g_UH[0][0][0];
  size_t nu = sizeof(g_UH) / 16u;
  for (size_t i = tid; i < nu; i += stride) pu[i] = z;
}

// ---------------------------------------------------------------- pre0: x @ Wx0^T + biases -> [t][c][128r]
__global__ __launch_bounds__(512) void pre0_kernel(const float* __restrict__ x,
                                                   const float* __restrict__ Wx0_w,
                                                   const float* __restrict__ Wx0_b,
                                                   const float* __restrict__ Wh0_b) {
  const unsigned t = blockIdx.x;
  const unsigned lane = threadIdx.x & 63u, w = threadIdx.x >> 6;
  const unsigned lrow = lane & 15u, lko = (lane >> 4) * 8u, crow = (lane >> 4) * 4u;
  const unsigned ncol0 = w * 64u;
  f32x4 z4 = {0.f, 0.f, 0.f, 0.f};
  f32x4 acc[8][4];
#pragma unroll
  for (int a = 0; a < 8; ++a)
#pragma unroll
    for (int b = 0; b < 4; ++b) acc[a][b] = z4;

  for (unsigned kk = 0; kk < 8u; ++kk) {
    unsigned k0 = kk * 32u + lko;
    bf16x8_t bfr[4];
#pragma unroll
    for (unsigned nj = 0; nj < 4u; ++nj) {
      unsigned n = ncol0 + nj * 16u + lrow;
      bfr[nj] = cvt8f(Wx0_w + n * 256u + k0);
    }
#pragma unroll
    for (unsigned mi = 0; mi < 8u; ++mi) {
      unsigned m = mi * 16u + lrow;
      bf16x8_t afr = cvt8f(x + ((size_t)m * 1024u + t) * 256u + k0);
#pragma unroll
      for (unsigned nj = 0; nj < 4u; ++nj)
        acc[mi][nj] = MF(afr, bfr[nj], acc[mi][nj]);
    }
  }
#pragma unroll
  for (unsigned mi = 0; mi < 8u; ++mi)
#pragma unroll
    for (unsigned nj = 0; nj < 4u; ++nj) {
      unsigned col = ncol0 + nj * 16u + lrow;
      u64 pv = 0ull;
#pragma unroll
      for (unsigned r = 0; r < 4u; ++r) {
        float v = acc[mi][nj][r] + Wx0_b[col] + Wh0_b[col];
        pv |= ((u64)f2bf(v)) << (16u * r);
      }
      *(u64*)(&g_pre0T[((size_t)t * 512u + col) * 128u + mi * 16u + crow]) = pv;
    }
}

// ---------------------------------------------------------------- persistent recurrence
// STAGE: 0 = L0 (h0 self-loop + pre0), 1 = U (U = h0@Wx1^T + b1), 2 = C (h1 self-loop + U)
template<int STAGE>
__device__ __forceinline__ void run_role(unsigned ch, unsigned hh, unsigned char* smem) {
  const unsigned tid = threadIdx.x;
  const unsigned lane = tid & 63u, w = tid >> 6;            // 8 waves
  const unsigned lrow = lane & 15u, kq = (lane >> 4) * 8u, crow4 = (lane >> 4) * 4u;
  const unsigned n0 = hh * 256u + w * 32u + lrow;           // output col (per lane)
  const unsigned cl = w * 32u + lrow;                       // col local to own half
  const unsigned row_c = tid >> 5, c8 = tid & 31u;          // cooperative chunk map
  const unsigned swz = (lrow & 7u) << 4;
  const unsigned swc = (row_c & 7u) << 4;

  // ---- B weights (compiler may rematerialize from L2 -- harmless w/ drain-all) ----
  bf16x8_t wB0[16], wB1[16];
  {
    const unsigned short* wp = g_W[STAGE];
#pragma unroll
    for (int f = 0; f < 16; ++f) {
      unsigned kfl = (STAGE == 1) ? (unsigned)f
                                  : ((f < 8) ? hh * 8u + (unsigned)f : (1u - hh) * 8u + (unsigned)(f - 8));
      wB0[f] = *(const bf16x8_t*)(wp + ((size_t)n0 * 512u + kfl * 32u + kq));
      wB1[f] = *(const bf16x8_t*)(wp + ((size_t)(n0 + 16u) * 512u + kfl * 32u + kq));
    }
  }
  float bu0 = 0.f, bu1 = 0.f;
  if (STAGE == 1) { bu0 = g_b1[n0]; bu1 = g_b1[n0 + 16u]; }

  const unsigned short* aB = (STAGE == 2) ? &g_h1H[ch][0][0] : &g_h0H[ch][0][0];
  unsigned short* oB = (STAGE == 0) ? &g_h0H[ch][0][0] : &g_h1H[ch][0][0];

  // LDS prefill: own slot-1 region = decoded zeros (read at t=0)
  if (STAGE != 1) {
    for (unsigned i = tid; i < 2048u; i += 512u) ((unsigned*)(smem + 8192u))[i] = 0u;
    __syncthreads();
  }

  const f32x4 z4 = {0.f, 0.f, 0.f, 0.f};

  for (unsigned t = 0; t < 1024u; ++t) {
    bf16x8_t X0, X1, X2, X3, X4, X5, X6, X7, X8, X9, X10, X11, X12, X13, X14, X15;
    f32x4 acc0 = z4, acc1 = z4;

    if constexpr (STAGE != 1) {
      u64 p0a = 0ull, p0b = 0ull;
      u32x4 ur0 = {0u,0u,0u,0u}, ur1 = {0u,0u,0u,0u};
      // ---- cooperative sibling-half load: ONE 16B sc1 chunk per thread ----
      const char* sibAddr = (const char*)aB + (size_t)t * 16384u
                            + row_c * 1024u + (1u - hh) * 512u + c8 * 16u;
      bf16x8_t sib;
      LDG16(sib, sibAddr, 0);
      if constexpr (STAGE == 0) {
        const unsigned short* pp = g_pre0T + ((size_t)t * 512u + n0) * 128u + ch * 16u + crow4;
        p0a = *(const u64*)pp;
        p0b = *(const u64*)(pp + 2048u);
      } else {
        const unsigned* pU = &g_UH[ch][t][(size_t)n0 * 16u + crow4];
        LDG16(ur0, pU, 0); LDG16(ur1, pU, 1024);
      }
      WAITV0;                                   // sib chunk + U landed; prev stores drained
      { bool ok = vfrag(sib); unsigned sp = 0;
        while (__any(!ok) && ++sp < SPIN_CAP) { LDG16(sib, sibAddr, 0); WAITV0; ok = vfrag(sib); } }
      *(bf16x8_t*)(smem + 16384u + row_c * 512u + ((c8 * 16u) ^ swc)) = dec(sib);

      // ---- own frags (LDS, ready since prev body) + MFMA 0-7 while others write sib ----
      const unsigned rdB = ((t + 1u) & 1u) * 8192u;
#define LRDO(F) X##F = *(const bf16x8_t*)(smem + rdB + lrow * 512u + ((((unsigned)(F) * 32u + kq) * 2u) ^ swz))
      LRDO(0); LRDO(1); LRDO(2); LRDO(3); LRDO(4); LRDO(5); LRDO(6); LRDO(7);
#undef LRDO
#define MM(F) do { acc0 = MF(X##F, wB0[F], acc0); acc1 = MF(X##F, wB1[F], acc1); } while (0)
      MM(0); MM(1); MM(2); MM(3); MM(4); MM(5); MM(6); MM(7);

      __syncthreads();                          // sib region complete
#define LRDS(F) X##F = *(const bf16x8_t*)(smem + 16384u + lrow * 512u + (((((unsigned)(F) - 8u) * 32u + kq) * 2u) ^ swz))
      LRDS(8); LRDS(9); LRDS(10); LRDS(11); LRDS(12); LRDS(13); LRDS(14); LRDS(15);
#undef LRDS
      MM(8); MM(9); MM(10); MM(11); MM(12); MM(13); MM(14); MM(15);
#undef MM

      if constexpr (STAGE == 2) {               // U validated after MFMAs (off critical path)
        const unsigned* pU2 = &g_UH[ch][t][(size_t)n0 * 16u + crow4];
        bool okU = vu4(ur0) && vu4(ur1);
        unsigned spu = 0;
        while (__any(!okU) && ++spu < SPIN_CAP) {
          LDG16(ur0, pU2, 0); LDG16(ur1, pU2, 1024);
          WAITV0;
          okU = vu4(ur0) && vu4(ur1);
        }
      }

      // ---- epilogue: tanh -> own-LDS slot (t&1) ----
      f32x4 u0 = decf(ur0), u1 = decf(ur1);
      float e0, e1, e2, e3, f0, f1, f2, f3;
      if constexpr (STAGE == 0) {
        e0 = bf2f((unsigned short)(p0a));        e1 = bf2f((unsigned short)(p0a >> 16));
        e2 = bf2f((unsigned short)(p0a >> 32));  e3 = bf2f((unsigned short)(p0a >> 48));
        f0 = bf2f((unsigned short)(p0b));        f1 = bf2f((unsigned short)(p0b >> 16));
        f2 = bf2f((unsigned short)(p0b >> 32));  f3 = bf2f((unsigned short)(p0b >> 48));
      } else {
        e0 = u0[0]; e1 = u0[1]; e2 = u0[2]; e3 = u0[3];
        f0 = u1[0]; f1 = u1[1]; f2 = u1[2]; f3 = u1[3];
      }
      const unsigned wrB = (t & 1u) * 8192u;
#define EMIT(J, ACC, EV, COFF) do { \
        unsigned hv = f2bf(tanh_fast((ACC)[J] + (EV))); \
        unsigned r_ = crow4 + (J); \
        *(unsigned short*)(smem + wrB + r_ * 512u + ((((cl + (COFF)) * 2u)) ^ ((r_ & 7u) << 4))) = (unsigned short)hv; \
      } while (0)
      EMIT(0, acc0, e0, 0u);  EMIT(1, acc0, e1, 0u);
      EMIT(2, acc0, e2, 0u);  EMIT(3, acc0, e3, 0u);
      EMIT(0, acc1, f0, 16u); EMIT(1, acc1, f1, 16u);
      EMIT(2, acc1, f2, 16u); EMIT(3, acc1, f3, 16u);
#undef EMIT
      __syncthreads();                          // own tile complete
      // ---- cooperative IC store: one full-line 16B encoded chunk per thread ----
      {
        u32x4 chunk = *(const u32x4*)(smem + wrB + row_c * 512u + ((c8 * 16u) ^ swc));
        chunk[0] = ~chunk[0]; chunk[1] = ~chunk[1]; chunk[2] = ~chunk[2]; chunk[3] = ~chunk[3];
        char* hoc = (char*)oB + (size_t)(t + 1u) * 16384u + row_c * 1024u + hh * 512u + c8 * 16u;
        ST16(hoc, 0, chunk);                    // fire-and-forget
      }
    } else {
      // ---- U stage: cooperative full-slot load (16KB = 2 chunks/thread) ----
      const char* uSrc = (const char*)&g_h0H[ch][0][0] + (size_t)(t + 1u) * 16384u
                         + row_c * 1024u + c8 * 16u;
      bf16x8_t cA, cB;
      LDG16(cA, uSrc, 0); LDG16(cB, uSrc, 512);
      WAITV0;
      { bool ok = vfrag(cA) && vfrag(cB); unsigned sp = 0;
        while (__any(!ok) && ++sp < SPIN_CAP) {
          LDG16(cA, uSrc, 0); LDG16(cB, uSrc, 512);
          WAITV0;
          ok = vfrag(cA) && vfrag(cB);
        } }
      *(bf16x8_t*)(smem + row_c * 1024u + ((c8 * 16u) ^ swc)) = dec(cA);
      *(bf16x8_t*)(smem + row_c * 1024u + ((512u + c8 * 16u) ^ swc)) = dec(cB);
      __syncthreads();                          // slot staged
#define LRDU(F) X##F = *(const bf16x8_t*)(smem + lrow * 1024u + ((((unsigned)(F) * 32u + kq) * 2u) ^ swz))
      LRDU(0); LRDU(1); LRDU(2); LRDU(3); LRDU(4); LRDU(5); LRDU(6); LRDU(7);
      LRDU(8); LRDU(9); LRDU(10); LRDU(11); LRDU(12); LRDU(13); LRDU(14); LRDU(15);
#undef LRDU
#define MM(F) do { acc0 = MF(X##F, wB0[F], acc0); acc1 = MF(X##F, wB1[F], acc1); } while (0)
      MM(0); MM(1); MM(2); MM(3); MM(4); MM(5); MM(6); MM(7);
      MM(8); MM(9); MM(10); MM(11); MM(12); MM(13); MM(14); MM(15);
#undef MM
      {
        char* uo = (char*)&g_UH[ch][t][0] + ((size_t)n0 * 16u + crow4) * 4u;
        u32x4 o;
        o[0] = ~__float_as_uint(acc0[0] + bu0); o[1] = ~__float_as_uint(acc0[1] + bu0);
        o[2] = ~__float_as_uint(acc0[2] + bu0); o[3] = ~__float_as_uint(acc0[3] + bu0);
        ST16(uo, 0, o);
        o[0] = ~__float_as_uint(acc1[0] + bu1); o[1] = ~__float_as_uint(acc1[1] + bu1);
        o[2] = ~__float_as_uint(acc1[2] + bu1); o[3] = ~__float_as_uint(acc1[3] + bu1);
        ST16(uo, 1024, o);                      // fire-and-forget
      }
      __syncthreads();                          // guard LDS before next overwrite
    }
  }
  WAITV0;                                       // drain final stores
}

__global__ __launch_bounds__(512, 1) void rnn_kernel() {
  __shared__ __align__(16) unsigned char smem[24576];
  const unsigned wg = blockIdx.x;               // 48 WGs
  const unsigned ch = wg / 6u;
  const unsigned r = wg % 6u;
  const unsigned stage = r >> 1, hh = r & 1u;
  if (stage == 0u) run_role<0>(ch, hh, smem);
  else if (stage == 1u) run_role<1>(ch, hh, smem);
  else run_role<2>(ch, hh, smem);
}

// ---------------------------------------------------------------- fc: h1_final @ fc_w^T + fc_b
__global__ __launch_bounds__(256) void fc_kernel(const float* __restrict__ fc_w,
                                                 const float* __restrict__ fc_b,
                                                 float* __restrict__ out) {
  const unsigned wg = blockIdx.x;
  const unsigned lane = threadIdx.x & 63u, w = threadIdx.x >> 6;
  const unsigned lrow = lane & 15u, lko = (lane >> 4) * 8u, crow = (lane >> 4) * 4u;
  const unsigned n0 = wg * 64u + w * 16u;
  f32x4 z4 = {0.f, 0.f, 0.f, 0.f};
  f32x4 acc[8];
#pragma unroll
  for (int a = 0; a < 8; ++a) acc[a] = z4;
  const unsigned n = n0 + lrow;
  for (unsigned kk = 0; kk < 16u; ++kk) {
    unsigned k0 = kk * 32u + lko;
    bf16x8_t bfr = {0, 0, 0, 0, 0, 0, 0, 0};
    if (n < 1000u) bfr = cvt8f(fc_w + n * 512u + k0);
#pragma unroll
    for (unsigned mi = 0; mi < 8u; ++mi) {
      bf16x8_t afr = dec(*(const bf16x8_t*)(&g_h1H[mi][1024][lrow * 512u + k0]));  // ~h1[1023]
      acc[mi] = MF(afr, bfr, acc[mi]);
    }
  }
#pragma unroll
  for (unsigned mi = 0; mi < 8u; ++mi)
#pragma unroll
    for (unsigned rr = 0; rr < 4u; ++rr) {
      unsigned row = mi * 16u + crow + rr;
      unsigned col = n0 + lrow;
      if (col < 1000u) out[row * 1000u + col] = acc[mi][rr] + fc_b[col];
    }
}

// ---------------------------------------------------------------- launch
extern "C" void kernel_launch(void* const* d_in, const int* in_sizes, int n_in,
                              void* d_out, int out_size, void* d_ws, size_t ws_size,
                              hipStream_t stream) {
  (void)in_sizes; (void)n_in; (void)out_size; (void)d_ws; (void)ws_size;
  const float* x     = (const float*)d_in[0];
  const float* Wx0_w = (const float*)d_in[1];
  const float* Wx0_b = (const float*)d_in[2];
  const float* Wh0_w = (const float*)d_in[3];
  const float* Wh0_b = (const float*)d_in[4];
  const float* Wx1_w = (const float*)d_in[5];
  const float* Wx1_b = (const float*)d_in[6];
  const float* Wh1_w = (const float*)d_in[7];
  const float* Wh1_b = (const float*)d_in[8];
  const float* fc_w  = (const float*)d_in[9];
  const float* fc_b  = (const float*)d_in[10];

  prep_kernel<<<1024, 256, 0, stream>>>(Wh0_w, Wx1_w, Wh1_w, Wx1_b, Wh1_b);
  pre0_kernel<<<1024, 512, 0, stream>>>(x, Wx0_w, Wx0_b, Wh0_b);
  rnn_kernel<<<48, 512, 0, stream>>>();
  fc_kernel<<<16, 256, 0, stream>>>(fc_w, fc_b, (float*)d_out);
}